// Round 8
// baseline (220.440 us; speedup 1.0000x reference)
//
#include <hip/hip_runtime.h>
#include <hip/hip_bf16.h>

#define N_NODES 10000
#define N_EDGES 320000
#define B_PRE   80
#define EPB     (N_EDGES / B_PRE)   // 4000
#define SLK     130                 // GEMM LDS row stride (halves): 65 dw, odd -> 16-bank spread

typedef __attribute__((ext_vector_type(8))) _Float16 half8;
typedef __attribute__((ext_vector_type(4))) _Float16 half4;
typedef __attribute__((ext_vector_type(4))) float floatx4;

// ---- ws offsets (bytes), total ~16.95 MB ----
#define OFF_RS    0           // rs: 10001 int
#define OFF_INVC  40960       // invc: 10000 f32
#define OFF_S2    81920       // s2: 20000 f32
#define OFF_COLV  163840      // colv: 320000 u16
#define OFF_WCAT  806912      // wcat2T: 3*256*512 f16 = 786432 B
#define OFF_HA    1593344     // hA: 10000*256 f16
#define OFF_HB    6713344     // hB: 10000*256 f16
#define OFF_G     11833344    // g:  10000*256 f16
// preproc scratch aliased into g (dead until first k_aggr):
#define OFF_PERC  OFF_G                   // 80*10000 u16 = 1.6 MB
#define OFF_BASE  (OFF_G + 1600000)       // 80*10000 int = 3.2 MB
#define OFF_CTOT  (OFF_G + 4800000)       // 10000 int = 40 KB
#define OFF_TICK  (OFF_G + 4840960)       // 1 int ticket
// s2 partial planes (2 x 80*10000 f32 = 6.4 MB) live in d_out (dead until final gemm2)

// ---------------- fused: per-block degree count + s2 partials (0..79)
//                  + weight pack (80..463) + x->f16 convert (464..1088) ----------------
// LDS = hist 40K + sfl 40K = 80KB -> 2 blocks/CU for the streaming blocks too.
__global__ __launch_bounds__(1024) void k_prepc(const float4* __restrict__ x, half4* __restrict__ hA,
                                                const float* __restrict__ neigh_w, const float* __restrict__ node_w,
                                                _Float16* __restrict__ wcatT,
                                                const int* __restrict__ ei, const float* __restrict__ ea,
                                                unsigned short* __restrict__ percnt,
                                                float* __restrict__ s2px, float* __restrict__ s2py,
                                                int* __restrict__ tick) {
  __shared__ int   hist[N_NODES];               // 40KB; aliased as transpose tile by pack blocks
  __shared__ float sfl[N_NODES];                // 40KB edge-attr partial sums (one component at a time)
  const int tid = threadIdx.x, b = blockIdx.x;

  if (b == 0 && tid == 0) *tick = 0;            // reset ticket for k_base (stream-ordered)

  if (b < B_PRE) {
    // ---- degree count + edge-attr x-partials (LDS atomics, CU-local) ----
    for (int n = tid; n < N_NODES; n += 1024) { hist[n] = 0; sfl[n] = 0.f; }
    __syncthreads();
    const int e0 = b * EPB;
    int   dreg[4]; float ayreg[4]; int cnt = 0;
    for (int e = e0 + tid; e < e0 + EPB; e += 1024) {
      int d = ei[N_EDGES + e];
      float2 a = ((const float2*)ea)[e];
      atomicAdd(&hist[d], 1);
      atomicAdd(&sfl[d], a.x);                  // ds_add_f32
      dreg[cnt] = d; ayreg[cnt] = a.y; ++cnt;   // keep for pass 2 (<=4 per thread)
    }
    __syncthreads();
    for (int n = tid; n < N_NODES; n += 1024) {
      percnt[b * N_NODES + n] = (unsigned short)hist[n];
      s2px[b * N_NODES + n] = sfl[n];           // coalesced f32 store
    }
    __syncthreads();
    for (int n = tid; n < N_NODES; n += 1024) sfl[n] = 0.f;
    __syncthreads();
    for (int i = 0; i < cnt; ++i) atomicAdd(&sfl[dreg[i]], ayreg[i]);
    __syncthreads();
    for (int n = tid; n < N_NODES; n += 1024)
      s2py[b * N_NODES + n] = sfl[n];
    return;
  }
  if (b < B_PRE + 384) {
    // ---- pack B^T: wcat2T[l][n(256)][k(512)] = (k<256 ? neigh_w[l][k][n] : node_w[l][k-256][n])
    float (*t)[33] = (float(*)[33])hist;          // 32x33 tile aliased over hist
    const int bb = b - B_PRE;                     // 384 = 16 k-tiles x 8 n-tiles x 3 layers
    const int k0 = (bb & 15) * 32;
    const int n0 = ((bb >> 4) & 7) * 32;
    const int l  = bb >> 7;
    const int r = tid >> 5, c = tid & 31;         // 32x32 = 1024 threads, 1 elem each
    const float* src = (k0 < 256) ? neigh_w : node_w;
    const int kb = (k0 < 256) ? k0 : (k0 - 256);
    t[r][c] = src[l * 65536 + (kb + r) * 256 + (n0 + c)];       // coalesced in n
    __syncthreads();
    wcatT[(size_t)l * 131072 + (n0 + r) * 512 + (k0 + c)] = (_Float16)t[c][r];  // coalesced in k
    return;
  }
  // ---- x -> f16 convert: 625 blocks x 1024 = 640000 float4 exactly ----
  int i = (b - (B_PRE + 384)) * 1024 + tid;
  float4 v = x[i];
  half4 h; h.x = (_Float16)v.x; h.y = (_Float16)v.y; h.z = (_Float16)v.z; h.w = (_Float16)v.w;
  hA[i] = h;
}

// blocks 0..39: per-node cross-block prefix + degree total; last-done block also runs the
// exclusive scan (fused k_scan via device ticket). blocks 40..79: s2 plane reduce.
__global__ __launch_bounds__(256) void k_base(const unsigned short* __restrict__ percnt,
                                              const float* __restrict__ s2px, const float* __restrict__ s2py,
                                              int* __restrict__ prefix, int* __restrict__ cnttot,
                                              int* __restrict__ rs, float* __restrict__ invc,
                                              float* __restrict__ s2, int* __restrict__ tick) {
  const int tid = threadIdx.x, b = blockIdx.x;
  if (b >= 40) {
    // ---- s2 final reduce (independent of scan; consumed only by gemm2) ----
    int n = (b - 40) * 256 + tid;
    if (n >= N_NODES) return;
    float sx = 0.f, sy = 0.f;
    for (int bb = 0; bb < B_PRE; ++bb) {
      sx += s2px[bb * N_NODES + n];
      sy += s2py[bb * N_NODES + n];
    }
    s2[2 * n] = sx; s2[2 * n + 1] = sy;
    return;
  }
  // ---- prefix + cnttot ----
  {
    int n = b * 256 + tid;
    if (n < N_NODES) {
      int s = 0;
      for (int bb = 0; bb < B_PRE; ++bb) {
        prefix[bb * N_NODES + n] = s;
        s += (int)percnt[bb * N_NODES + n];
      }
      cnttot[n] = s;
    }
  }
  // ---- ticket: last of the 40 prefix blocks runs the scan ----
  __shared__ int lastflag;
  __threadfence();
  if (tid == 0) lastflag = (atomicAdd(tick, 1) == 39);
  __syncthreads();
  if (!lastflag) return;
  __threadfence();

  __shared__ int slds[256];
  const int base = tid * 40;                     // 256*40 = 10240 >= 10000
  int loc[40];
  int sum = 0;
#pragma unroll
  for (int i = 0; i < 40; ++i) {
    int idx = base + i;
    int v = (idx < N_NODES) ? cnttot[idx] : 0;
    loc[i] = v; sum += v;
  }
  slds[tid] = sum; __syncthreads();
  for (int off = 1; off < 256; off <<= 1) {
    int v = 0;
    if (tid >= off) v = slds[tid - off];
    __syncthreads();
    if (tid >= off) slds[tid] += v;
    __syncthreads();
  }
  int ex = slds[tid] - sum;
#pragma unroll
  for (int i = 0; i < 40; ++i) {
    int idx = base + i;
    if (idx < N_NODES) {
      rs[idx] = ex; ex += loc[i];
      invc[idx] = (loc[i] > 0) ? (1.0f / (float)loc[i]) : 0.0f;
    }
  }
  if (tid == 255) rs[N_NODES] = slds[255];
}

// scatter colv into CSR order (plain stores; no edge-attr work)
__global__ __launch_bounds__(1024) void k_scat(const int* __restrict__ ei,
                                               const int* __restrict__ prefix, const int* __restrict__ rs,
                                               unsigned short* __restrict__ colv) {
  __shared__ int cur[N_NODES];
  const int t = threadIdx.x, b = blockIdx.x;
  for (int n = t; n < N_NODES; n += 1024)
    cur[n] = rs[n] + prefix[b * N_NODES + n];
  __syncthreads();
  const int e0 = b * EPB;
  for (int e = e0 + t; e < e0 + EPB; e += 1024) {
    int d = ei[N_EDGES + e];
    int src = ei[e];
    int pos = atomicAdd(&cur[d], 1);             // LDS atomic
    colv[pos] = (unsigned short)src;
  }
}

// ---------------- aggregate h first (linearity): g[n] = invc[n] * sum_{src in N(n)} h[src] ----------------
// One node per wave (10000 waves), 16 edges / 8 row-loads in flight per half-wave.
__global__ __launch_bounds__(256) void k_aggr(const int* __restrict__ rs, const unsigned short* __restrict__ colv,
                                              const float* __restrict__ invc,
                                              const _Float16* __restrict__ H, _Float16* __restrict__ Gm) {
  const int wv   = threadIdx.x >> 6;
  const int lane = threadIdx.x & 63;
  const int hf   = lane >> 5;
  const int l5   = lane & 31;
  const int n = blockIdx.x * 4 + wv;   // 2500*4 == N_NODES
  int beg = rs[n], end = rs[n + 1];
  beg = max(0, min(beg, N_EDGES));
  end = max(beg, min(end, N_EDGES));
  const int co = l5 * 8;               // this half-lane's channel offset (x8 f16)

  half8 a0 = (half8)(_Float16)0.f, a1 = (half8)(_Float16)0.f;
  half8 a2 = (half8)(_Float16)0.f, a3 = (half8)(_Float16)0.f;
  half8 a4 = (half8)(_Float16)0.f, a5 = (half8)(_Float16)0.f;
  half8 a6 = (half8)(_Float16)0.f, a7 = (half8)(_Float16)0.f;
  for (int base = beg; base < end; base += 64) {
    const int cnt = min(64, end - base);
    int myIdx = 0;
    if (base + lane < end) myIdx = (int)colv[base + lane];   // coalesced index load
    int j = 0;
    for (; j + 16 <= cnt; j += 16) {                         // 16 edges / 8 loads in flight
      int s[8];
#pragma unroll
      for (int k = 0; k < 8; ++k) s[k] = __shfl(myIdx, j + 2 * k + hf);
      half8 v[8];
#pragma unroll
      for (int k = 0; k < 8; ++k) v[k] = *(const half8*)(H + (size_t)s[k] * 256 + co);
      a0 += v[0]; a1 += v[1]; a2 += v[2]; a3 += v[3];
      a4 += v[4]; a5 += v[5]; a6 += v[6]; a7 += v[7];
    }
    for (; j + 8 <= cnt; j += 8) {                           // 8 edges / 4 loads
      int s0 = __shfl(myIdx, j + hf);
      int s1 = __shfl(myIdx, j + 2 + hf);
      int s2i = __shfl(myIdx, j + 4 + hf);
      int s3 = __shfl(myIdx, j + 6 + hf);
      half8 v0 = *(const half8*)(H + (size_t)s0 * 256 + co);
      half8 v1 = *(const half8*)(H + (size_t)s1 * 256 + co);
      half8 v2 = *(const half8*)(H + (size_t)s2i * 256 + co);
      half8 v3 = *(const half8*)(H + (size_t)s3 * 256 + co);
      a0 += v0; a1 += v1; a2 += v2; a3 += v3;
    }
    for (; j + 2 <= cnt; j += 2) {
      int s0 = __shfl(myIdx, j + hf);
      a0 += *(const half8*)(H + (size_t)s0 * 256 + co);
    }
    if (j < cnt) {
      int s0 = __shfl(myIdx, j);
      if (hf == 0)
        a0 += *(const half8*)(H + (size_t)s0 * 256 + co);
    }
  }
  half8 acc0 = ((a0 + a4) + (a1 + a5)) + ((a2 + a6) + (a3 + a7));
  // combine the two half-waves (same channels, different edges)
  union { half8 h; unsigned int u[4]; } me, ot;
  me.h = acc0;
#pragma unroll
  for (int r = 0; r < 4; ++r) ot.u[r] = (unsigned int)__shfl_xor((int)me.u[r], 32);
  acc0 = me.h + ot.h;

  if (hf == 0) {
    const float ic = invc[n];
    half8 o;
#pragma unroll
    for (int k = 0; k < 8; ++k) o[k] = (_Float16)((float)acc0[k] * ic);
    *(half8*)(Gm + (size_t)n * 256 + co) = o;   // 32 lanes x 16B = full 512B row
  }
}

// ---------------- GEMM [g | h] (Nx512) @ B^T(256x512) + fused update + KAF epilogue ----------------
// 64x64 tile, BK=128, K=512 -> 4 kt iters. LDS 38.4KB -> 4 blocks/CU.
__global__ __launch_bounds__(256) void k_gemm2(const _Float16* __restrict__ Gm,  // [N][256] f16
                                               const _Float16* __restrict__ Hm,  // [N][256] f16
                                               const _Float16* __restrict__ BT,  // [256][512] f16
                                               const float* __restrict__ ew,     // [2][256] f32
                                               const float* __restrict__ bias,   // [256]    f32
                                               const float* __restrict__ alpha,  // [256][20] f32
                                               const float* __restrict__ invc,
                                               const float* __restrict__ s2,
                                               _Float16* __restrict__ hout, float* __restrict__ fout,
                                               int final_layer) {
  __shared__ _Float16 As[64 * SLK];
  __shared__ _Float16 Bs[64 * SLK];
  __shared__ float alds[64 * 20];      // alpha rows for this block's 64 output cols
  const int tid = threadIdx.x;
  const int wv = tid >> 6;
  const int lane = tid & 63;
  const int m0 = blockIdx.x * 64;
  const int n0 = blockIdx.y * 64;
  const int wy = wv >> 1, wx = wv & 1;

#pragma unroll
  for (int ii = 0; ii < 5; ++ii)       // 64 rows x 20 = 1280 floats, contiguous in alpha
    alds[tid + 256 * ii] = alpha[n0 * 20 + tid + 256 * ii];

  floatx4 acc[2][2];
#pragma unroll
  for (int i = 0; i < 2; ++i)
#pragma unroll
    for (int j = 0; j < 2; ++j) acc[i][j] = (floatx4){0.f, 0.f, 0.f, 0.f};

  const int mrow = 32 * wy + (lane & 15);
  const int nrow = 32 * wx + (lane & 15);
  const int q8 = (lane >> 4) * 8;

#pragma unroll
  for (int kt = 0; kt < 4; ++kt) {     // K=512 / BK=128
    const _Float16* Asrc = (kt < 2) ? Gm : Hm;   // first 256 k's: g, last 256: h
    const int ko = (kt & 1) * 128;
    half8 av[4], bv[4];
#pragma unroll
    for (int c = 0; c < 4; ++c) {
      int ch = tid + 256 * c;            // 0..1023
      int row = ch >> 4;
      int off = (ch & 15) * 8;
      int arow = m0 + row; if (arow >= N_NODES) arow = N_NODES - 1;
      av[c] = *(const half8*)(Asrc + (size_t)arow * 256 + ko + off);
      bv[c] = *(const half8*)(BT + (size_t)(n0 + row) * 512 + kt * 128 + off);
    }
    __syncthreads();                     // prev iter's LDS reads complete
#pragma unroll
    for (int c = 0; c < 4; ++c) {
      int ch = tid + 256 * c;
      int row = ch >> 4;
      int off = (ch & 15) * 8;
      *(half8*)&As[row * SLK + off] = av[c];
      *(half8*)&Bs[row * SLK + off] = bv[c];
    }
    __syncthreads();
#pragma unroll
    for (int ks = 0; ks < 4; ++ks) {
      const int kb = ks * 32 + q8;
      half8 af0 = *(const half8*)&As[mrow * SLK + kb];
      half8 af1 = *(const half8*)&As[(mrow + 16) * SLK + kb];
      half8 bf0 = *(const half8*)&Bs[nrow * SLK + kb];
      half8 bf1 = *(const half8*)&Bs[(nrow + 16) * SLK + kb];
      acc[0][0] = __builtin_amdgcn_mfma_f32_16x16x32_f16(af0, bf0, acc[0][0], 0, 0, 0);
      acc[0][1] = __builtin_amdgcn_mfma_f32_16x16x32_f16(af0, bf1, acc[0][1], 0, 0, 0);
      acc[1][0] = __builtin_amdgcn_mfma_f32_16x16x32_f16(af1, bf0, acc[1][0], 0, 0, 0);
      acc[1][1] = __builtin_amdgcn_mfma_f32_16x16x32_f16(af1, bf1, acc[1][1], 0, 0, 0);
    }
  }

  // ---- fused update + KAF epilogue ----
  // C/D layout: col = lane&15, row = 4*(lane>>4) + r
  const int rowb = m0 + 32 * wy + 4 * (lane >> 4);
  const int clb  = 32 * wx + (lane & 15);    // local col in [0,64)
  float icr[2][4], t0r[2][4], t1r[2][4];
#pragma unroll
  for (int i = 0; i < 2; ++i)
#pragma unroll
    for (int r = 0; r < 4; ++r) {
      int rw = rowb + 16 * i + r;
      int rc = (rw < N_NODES) ? rw : (N_NODES - 1);
      icr[i][r] = invc[rc];
      t0r[i][r] = s2[2 * rc];
      t1r[i][r] = s2[2 * rc + 1];
    }
  const float WM = 0.7788007831f;      // exp(-0.25)
#pragma unroll
  for (int j = 0; j < 2; ++j) {
    const int cl = clb + 16 * j;
    const int cn = n0 + cl;
    const float e0 = ew[cn], e1 = ew[256 + cn], bi = bias[cn];
    float a20[20];
#pragma unroll
    for (int q = 0; q < 5; ++q)
      *(float4*)&a20[4 * q] = *(const float4*)&alds[cl * 20 + 4 * q];  // stride 20 dw: 2-way bank (free)
#pragma unroll
    for (int i = 0; i < 2; ++i) {
      float K[4], R[4], o[4];
#pragma unroll
      for (int r = 0; r < 4; ++r) {
        float sv = acc[i][j][r] + icr[i][r] * (t0r[i][r] * e0 + t1r[i][r] * e1) + bi;
        // KAF geometric recurrence: G=-0.705078125, 2G*dp=-0.59375, G*dp^2=-0.125 (exact)
        float tt = fminf(fmaxf(sv, -40.f), 40.f);
        float dd = tt + 4.0f;
        K[r] = __expf(-0.705078125f * dd * dd);
        R[r] = __expf(0.59375f * dd - 0.125f);
        o[r] = 0.f;
      }
#pragma unroll
      for (int d = 0; d < 20; ++d) {
        o[0] += a20[d] * K[0]; K[0] *= R[0]; R[0] *= WM;
        o[1] += a20[d] * K[1]; K[1] *= R[1]; R[1] *= WM;
        o[2] += a20[d] * K[2]; K[2] *= R[2]; R[2] *= WM;
        o[3] += a20[d] * K[3]; K[3] *= R[3]; R[3] *= WM;
      }
      const int rw0 = rowb + 16 * i;
      if (final_layer) {
#pragma unroll
        for (int r = 0; r < 4; ++r)
          if (rw0 + r < N_NODES) fout[(size_t)(rw0 + r) * 256 + cn] = o[r];
      } else {
#pragma unroll
        for (int r = 0; r < 4; ++r)
          if (rw0 + r < N_NODES) hout[(size_t)(rw0 + r) * 256 + cn] = (_Float16)o[r];
      }
    }
  }
}

// ---------------- launch ----------------
extern "C" void kernel_launch(void* const* d_in, const int* in_sizes, int n_in,
                              void* d_out, int out_size, void* d_ws, size_t ws_size,
                              hipStream_t stream) {
  const float* x       = (const float*)d_in[0];
  const int*   ei      = (const int*)d_in[1];
  const float* ea      = (const float*)d_in[2];
  const float* node_w  = (const float*)d_in[3];
  const float* edge_w  = (const float*)d_in[4];
  const float* neigh_w = (const float*)d_in[5];
  const float* bias    = (const float*)d_in[6];
  const float* alpha   = (const float*)d_in[7];

  char* w = (char*)d_ws;
  int*            rs     = (int*)(w + OFF_RS);
  float*          invc   = (float*)(w + OFF_INVC);
  float*          s2     = (float*)(w + OFF_S2);
  unsigned short* colv   = (unsigned short*)(w + OFF_COLV);
  _Float16*       wcatT  = (_Float16*)(w + OFF_WCAT);
  _Float16*       hA     = (_Float16*)(w + OFF_HA);
  _Float16*       hB     = (_Float16*)(w + OFF_HB);
  _Float16*       g      = (_Float16*)(w + OFF_G);
  unsigned short* percnt = (unsigned short*)(w + OFF_PERC);
  int*            prefix = (int*)(w + OFF_BASE);
  int*            cnttot = (int*)(w + OFF_CTOT);
  int*            tick   = (int*)(w + OFF_TICK);
  float*          fout   = (float*)d_out;
  float*          s2px   = (float*)d_out;                       // 3.2 MB plane
  float*          s2py   = (float*)((char*)d_out + 3200000);    // 3.2 MB plane (d_out dead until final gemm2)

  k_prepc<<<B_PRE + 384 + 625, 1024, 0, stream>>>((const float4*)x, (half4*)hA,
                                                  neigh_w, node_w, wcatT, ei, ea, percnt,
                                                  s2px, s2py, tick);
  k_base<<<80, 256, 0, stream>>>(percnt, s2px, s2py, prefix, cnttot, rs, invc, s2, tick);
  k_scat<<<B_PRE, 1024, 0, stream>>>(ei, prefix, rs, colv);

  _Float16* hin = hA;
  for (int l = 0; l < 3; ++l) {
    k_aggr<<<2500, 256, 0, stream>>>(rs, colv, invc, hin, g);
    _Float16* hout = (l == 0) ? hB : hA;
    k_gemm2<<<dim3(157, 4), 256, 0, stream>>>(g, hin, wcatT + (size_t)l * 131072,
                                              edge_w + l * 512, bias + l * 256, alpha + l * 5120,
                                              invc, s2, hout, fout, (l == 2) ? 1 : 0);
    hin = hout;
  }
}

// Round 10
// 219.073 us; speedup vs baseline: 1.0062x; 1.0062x over previous
//
#include <hip/hip_runtime.h>
#include <hip/hip_bf16.h>

#define N_NODES 10000
#define N_EDGES 320000
#define B_PRE   80
#define EPB     (N_EDGES / B_PRE)   // 4000
#define SLK     130                 // GEMM LDS row stride (halves): 65 dw, odd -> 16-bank spread

typedef __attribute__((ext_vector_type(8))) _Float16 half8;
typedef __attribute__((ext_vector_type(4))) _Float16 half4;
typedef __attribute__((ext_vector_type(4))) float floatx4;

// ---- ws offsets (bytes), total ~16.95 MB ----
#define OFF_RS    0           // rs: 10001 int
#define OFF_INVC  40960       // invc: 10000 f32
#define OFF_S2    81920       // s2: 20000 f32
#define OFF_COLV  163840      // colv: 320000 u16
#define OFF_WCAT  806912      // wcat2T: 3*256*512 f16 = 786432 B
#define OFF_HA    1593344     // hA: 10000*256 f16
#define OFF_HB    6713344     // hB: 10000*256 f16
#define OFF_G     11833344    // g:  10000*256 f16
// preproc scratch aliased into g (dead until first k_aggr):
#define OFF_PERC  OFF_G                   // 80*10000 u16 = 1.6 MB
#define OFF_BASE  (OFF_G + 1600000)       // 80*10000 int = 3.2 MB
#define OFF_CTOT  (OFF_G + 4800000)       // 10000 int = 40 KB
#define OFF_TICK  (OFF_G + 4840960)       // 1 int ticket
// s2 partials (80*10000 float2 = 6.4 MB) live in d_out (dead until final gemm2)

// ---------------- fused: per-block degree count + s2 partials (0..79)
//                  + weight pack (80..463) + x->f16 convert (464..1088) ----------------
// r7-verified one-pass version (120KB LDS on count blocks).
__global__ __launch_bounds__(1024) void k_prepc(const float4* __restrict__ x, half4* __restrict__ hA,
                                                const float* __restrict__ neigh_w, const float* __restrict__ node_w,
                                                _Float16* __restrict__ wcatT,
                                                const int* __restrict__ ei, const float* __restrict__ ea,
                                                unsigned short* __restrict__ percnt,
                                                float2* __restrict__ s2part, int* __restrict__ tick) {
  __shared__ int hist[N_NODES];                   // 40KB; aliased as transpose tile by pack blocks
  __shared__ float2 sxy[N_NODES];                 // 80KB edge-attr partial sums
  const int tid = threadIdx.x, b = blockIdx.x;

  if (b == 0 && tid == 0) *tick = 0;              // reset ticket for k_base (stream-ordered)

  if (b < B_PRE) {
    // ---- degree count + edge-attr partial sums (LDS atomics, CU-local) ----
    for (int n = tid; n < N_NODES; n += 1024) { hist[n] = 0; sxy[n] = make_float2(0.f, 0.f); }
    __syncthreads();
    const int e0 = b * EPB;
    for (int e = e0 + tid; e < e0 + EPB; e += 1024) {
      int d = ei[N_EDGES + e];
      float2 a = ((const float2*)ea)[e];
      atomicAdd(&hist[d], 1);
      atomicAdd(&sxy[d].x, a.x);                  // ds_add_f32
      atomicAdd(&sxy[d].y, a.y);
    }
    __syncthreads();
    for (int n = tid; n < N_NODES; n += 1024) {
      percnt[b * N_NODES + n] = (unsigned short)hist[n];
      s2part[b * N_NODES + n] = sxy[n];           // coalesced float2 store
    }
    return;
  }
  if (b < B_PRE + 384) {
    // ---- pack B^T: wcat2T[l][n(256)][k(512)] = (k<256 ? neigh_w[l][k][n] : node_w[l][k-256][n])
    float (*t)[33] = (float(*)[33])hist;          // 32x33 tile aliased over hist
    const int bb = b - B_PRE;                     // 384 = 16 k-tiles x 8 n-tiles x 3 layers
    const int k0 = (bb & 15) * 32;
    const int n0 = ((bb >> 4) & 7) * 32;
    const int l  = bb >> 7;
    const int r = tid >> 5, c = tid & 31;         // 32x32 = 1024 threads, 1 elem each
    const float* src = (k0 < 256) ? neigh_w : node_w;
    const int kb = (k0 < 256) ? k0 : (k0 - 256);
    t[r][c] = src[l * 65536 + (kb + r) * 256 + (n0 + c)];       // coalesced in n
    __syncthreads();
    wcatT[(size_t)l * 131072 + (n0 + r) * 512 + (k0 + c)] = (_Float16)t[c][r];  // coalesced in k
    return;
  }
  // ---- x -> f16 convert: 625 blocks x 1024 = 640000 float4 exactly ----
  int i = (b - (B_PRE + 384)) * 1024 + tid;
  float4 v = x[i];
  half4 h; h.x = (_Float16)v.x; h.y = (_Float16)v.y; h.z = (_Float16)v.z; h.w = (_Float16)v.w;
  hA[i] = h;
}

// blocks 0..39: per-node cross-block prefix + degree total; last-done block also runs the
// exclusive scan (fused k_scan via device ticket). blocks 40..79: s2 reduce.
__global__ __launch_bounds__(256) void k_base(const unsigned short* __restrict__ percnt,
                                              const float2* __restrict__ s2part,
                                              int* __restrict__ prefix, int* __restrict__ cnttot,
                                              int* __restrict__ rs, float* __restrict__ invc,
                                              float* __restrict__ s2, int* __restrict__ tick) {
  const int tid = threadIdx.x, b = blockIdx.x;
  if (b >= 40) {
    // ---- s2 final reduce (independent of scan; consumed only by gemm2) ----
    int n = (b - 40) * 256 + tid;
    if (n >= N_NODES) return;
    float sx = 0.f, sy = 0.f;
    for (int bb = 0; bb < B_PRE; ++bb) {
      float2 p = s2part[bb * N_NODES + n];
      sx += p.x; sy += p.y;
    }
    s2[2 * n] = sx; s2[2 * n + 1] = sy;
    return;
  }
  // ---- prefix + cnttot ----
  {
    int n = b * 256 + tid;
    if (n < N_NODES) {
      int s = 0;
      for (int bb = 0; bb < B_PRE; ++bb) {
        prefix[bb * N_NODES + n] = s;
        s += (int)percnt[bb * N_NODES + n];
      }
      cnttot[n] = s;
    }
  }
  // ---- ticket: last of the 40 prefix blocks runs the scan ----
  __shared__ int lastflag;
  __threadfence();
  if (tid == 0) lastflag = (atomicAdd(tick, 1) == 39);
  __syncthreads();
  if (!lastflag) return;
  __threadfence();

  __shared__ int slds[256];
  const int base = tid * 40;                     // 256*40 = 10240 >= 10000
  int loc[40];
  int sum = 0;
#pragma unroll
  for (int i = 0; i < 40; ++i) {
    int idx = base + i;
    int v = (idx < N_NODES) ? cnttot[idx] : 0;
    loc[i] = v; sum += v;
  }
  slds[tid] = sum; __syncthreads();
  for (int off = 1; off < 256; off <<= 1) {
    int v = 0;
    if (tid >= off) v = slds[tid - off];
    __syncthreads();
    if (tid >= off) slds[tid] += v;
    __syncthreads();
  }
  int ex = slds[tid] - sum;
#pragma unroll
  for (int i = 0; i < 40; ++i) {
    int idx = base + i;
    if (idx < N_NODES) {
      rs[idx] = ex; ex += loc[i];
      invc[idx] = (loc[i] > 0) ? (1.0f / (float)loc[i]) : 0.0f;
    }
  }
  if (tid == 255) rs[N_NODES] = slds[255];
}

// scatter colv into CSR order (plain stores; no edge-attr work)
__global__ __launch_bounds__(1024) void k_scat(const int* __restrict__ ei,
                                               const int* __restrict__ prefix, const int* __restrict__ rs,
                                               unsigned short* __restrict__ colv) {
  __shared__ int cur[N_NODES];
  const int t = threadIdx.x, b = blockIdx.x;
  for (int n = t; n < N_NODES; n += 1024)
    cur[n] = rs[n] + prefix[b * N_NODES + n];
  __syncthreads();
  const int e0 = b * EPB;
  for (int e = e0 + t; e < e0 + EPB; e += 1024) {
    int d = ei[N_EDGES + e];
    int src = ei[e];
    int pos = atomicAdd(&cur[d], 1);             // LDS atomic
    colv[pos] = (unsigned short)src;
  }
}

// ---------------- aggregate h first (linearity): g[n] = invc[n] * sum_{src in N(n)} h[src] ----------------
// One node per wave (10000 waves), 16 edges / 8 row-loads in flight per half-wave.
__global__ __launch_bounds__(256) void k_aggr(const int* __restrict__ rs, const unsigned short* __restrict__ colv,
                                              const float* __restrict__ invc,
                                              const _Float16* __restrict__ H, _Float16* __restrict__ Gm) {
  const int wv   = threadIdx.x >> 6;
  const int lane = threadIdx.x & 63;
  const int hf   = lane >> 5;
  const int l5   = lane & 31;
  const int n = blockIdx.x * 4 + wv;   // 2500*4 == N_NODES
  int beg = rs[n], end = rs[n + 1];
  beg = max(0, min(beg, N_EDGES));
  end = max(beg, min(end, N_EDGES));
  const int co = l5 * 8;               // this half-lane's channel offset (x8 f16)

  half8 a0 = (half8)(_Float16)0.f, a1 = (half8)(_Float16)0.f;
  half8 a2 = (half8)(_Float16)0.f, a3 = (half8)(_Float16)0.f;
  half8 a4 = (half8)(_Float16)0.f, a5 = (half8)(_Float16)0.f;
  half8 a6 = (half8)(_Float16)0.f, a7 = (half8)(_Float16)0.f;
  for (int base = beg; base < end; base += 64) {
    const int cnt = min(64, end - base);
    int myIdx = 0;
    if (base + lane < end) myIdx = (int)colv[base + lane];   // coalesced index load
    int j = 0;
    for (; j + 16 <= cnt; j += 16) {                         // 16 edges / 8 loads in flight
      int s[8];
#pragma unroll
      for (int k = 0; k < 8; ++k) s[k] = __shfl(myIdx, j + 2 * k + hf);
      half8 v[8];
#pragma unroll
      for (int k = 0; k < 8; ++k) v[k] = *(const half8*)(H + (size_t)s[k] * 256 + co);
      a0 += v[0]; a1 += v[1]; a2 += v[2]; a3 += v[3];
      a4 += v[4]; a5 += v[5]; a6 += v[6]; a7 += v[7];
    }
    for (; j + 8 <= cnt; j += 8) {                           // 8 edges / 4 loads
      int s0 = __shfl(myIdx, j + hf);
      int s1 = __shfl(myIdx, j + 2 + hf);
      int s2i = __shfl(myIdx, j + 4 + hf);
      int s3 = __shfl(myIdx, j + 6 + hf);
      half8 v0 = *(const half8*)(H + (size_t)s0 * 256 + co);
      half8 v1 = *(const half8*)(H + (size_t)s1 * 256 + co);
      half8 v2 = *(const half8*)(H + (size_t)s2i * 256 + co);
      half8 v3 = *(const half8*)(H + (size_t)s3 * 256 + co);
      a0 += v0; a1 += v1; a2 += v2; a3 += v3;
    }
    for (; j + 2 <= cnt; j += 2) {
      int s0 = __shfl(myIdx, j + hf);
      a0 += *(const half8*)(H + (size_t)s0 * 256 + co);
    }
    if (j < cnt) {
      int s0 = __shfl(myIdx, j);
      if (hf == 0)
        a0 += *(const half8*)(H + (size_t)s0 * 256 + co);
    }
  }
  half8 acc0 = ((a0 + a4) + (a1 + a5)) + ((a2 + a6) + (a3 + a7));
  // combine the two half-waves (same channels, different edges)
  union { half8 h; unsigned int u[4]; } me, ot;
  me.h = acc0;
#pragma unroll
  for (int r = 0; r < 4; ++r) ot.u[r] = (unsigned int)__shfl_xor((int)me.u[r], 32);
  acc0 = me.h + ot.h;

  if (hf == 0) {
    const float ic = invc[n];
    half8 o;
#pragma unroll
    for (int k = 0; k < 8; ++k) o[k] = (_Float16)((float)acc0[k] * ic);
    *(half8*)(Gm + (size_t)n * 256 + co) = o;   // 32 lanes x 16B = full 512B row
  }
}

// ---------------- GEMM [g | h] (Nx512) @ B^T(256x512) + fused update + KAF epilogue ----------------
// 64x64 tile, BK=128, K=512 -> 4 kt iters. LDS 38.4KB -> 4 blocks/CU.
__global__ __launch_bounds__(256) void k_gemm2(const _Float16* __restrict__ Gm,  // [N][256] f16
                                               const _Float16* __restrict__ Hm,  // [N][256] f16
                                               const _Float16* __restrict__ BT,  // [256][512] f16
                                               const float* __restrict__ ew,     // [2][256] f32
                                               const float* __restrict__ bias,   // [256]    f32
                                               const float* __restrict__ alpha,  // [256][20] f32
                                               const float* __restrict__ invc,
                                               const float* __restrict__ s2,
                                               _Float16* __restrict__ hout, float* __restrict__ fout,
                                               int final_layer) {
  __shared__ _Float16 As[64 * SLK];
  __shared__ _Float16 Bs[64 * SLK];
  __shared__ float alds[64 * 20];      // alpha rows for this block's 64 output cols
  const int tid = threadIdx.x;
  const int wv = tid >> 6;
  const int lane = tid & 63;
  const int m0 = blockIdx.x * 64;
  const int n0 = blockIdx.y * 64;
  const int wy = wv >> 1, wx = wv & 1;

#pragma unroll
  for (int ii = 0; ii < 5; ++ii)       // 64 rows x 20 = 1280 floats, contiguous in alpha
    alds[tid + 256 * ii] = alpha[n0 * 20 + tid + 256 * ii];

  floatx4 acc[2][2];
#pragma unroll
  for (int i = 0; i < 2; ++i)
#pragma unroll
    for (int j = 0; j < 2; ++j) acc[i][j] = (floatx4){0.f, 0.f, 0.f, 0.f};

  const int mrow = 32 * wy + (lane & 15);
  const int nrow = 32 * wx + (lane & 15);
  const int q8 = (lane >> 4) * 8;

#pragma unroll
  for (int kt = 0; kt < 4; ++kt) {     // K=512 / BK=128
    const _Float16* Asrc = (kt < 2) ? Gm : Hm;   // first 256 k's: g, last 256: h
    const int ko = (kt & 1) * 128;
    half8 av[4], bv[4];
#pragma unroll
    for (int c = 0; c < 4; ++c) {
      int ch = tid + 256 * c;            // 0..1023
      int row = ch >> 4;
      int off = (ch & 15) * 8;
      int arow = m0 + row; if (arow >= N_NODES) arow = N_NODES - 1;
      av[c] = *(const half8*)(Asrc + (size_t)arow * 256 + ko + off);
      bv[c] = *(const half8*)(BT + (size_t)(n0 + row) * 512 + kt * 128 + off);
    }
    __syncthreads();                     // prev iter's LDS reads complete
#pragma unroll
    for (int c = 0; c < 4; ++c) {
      int ch = tid + 256 * c;
      int row = ch >> 4;
      int off = (ch & 15) * 8;
      *(half8*)&As[row * SLK + off] = av[c];
      *(half8*)&Bs[row * SLK + off] = bv[c];
    }
    __syncthreads();
#pragma unroll
    for (int ks = 0; ks < 4; ++ks) {
      const int kb = ks * 32 + q8;
      half8 af0 = *(const half8*)&As[mrow * SLK + kb];
      half8 af1 = *(const half8*)&As[(mrow + 16) * SLK + kb];
      half8 bf0 = *(const half8*)&Bs[nrow * SLK + kb];
      half8 bf1 = *(const half8*)&Bs[(nrow + 16) * SLK + kb];
      acc[0][0] = __builtin_amdgcn_mfma_f32_16x16x32_f16(af0, bf0, acc[0][0], 0, 0, 0);
      acc[0][1] = __builtin_amdgcn_mfma_f32_16x16x32_f16(af0, bf1, acc[0][1], 0, 0, 0);
      acc[1][0] = __builtin_amdgcn_mfma_f32_16x16x32_f16(af1, bf0, acc[1][0], 0, 0, 0);
      acc[1][1] = __builtin_amdgcn_mfma_f32_16x16x32_f16(af1, bf1, acc[1][1], 0, 0, 0);
    }
  }

  // ---- fused update + KAF epilogue ----
  // C/D layout: col = lane&15, row = 4*(lane>>4) + r
  const int rowb = m0 + 32 * wy + 4 * (lane >> 4);
  const int clb  = 32 * wx + (lane & 15);    // local col in [0,64)
  float icr[2][4], t0r[2][4], t1r[2][4];
#pragma unroll
  for (int i = 0; i < 2; ++i)
#pragma unroll
    for (int r = 0; r < 4; ++r) {
      int rw = rowb + 16 * i + r;
      int rc = (rw < N_NODES) ? rw : (N_NODES - 1);
      icr[i][r] = invc[rc];
      t0r[i][r] = s2[2 * rc];
      t1r[i][r] = s2[2 * rc + 1];
    }
  const float WM = 0.7788007831f;      // exp(-0.25)
#pragma unroll
  for (int j = 0; j < 2; ++j) {
    const int cl = clb + 16 * j;
    const int cn = n0 + cl;
    const float e0 = ew[cn], e1 = ew[256 + cn], bi = bias[cn];
    float a20[20];
#pragma unroll
    for (int q = 0; q < 5; ++q)
      *(float4*)&a20[4 * q] = *(const float4*)&alds[cl * 20 + 4 * q];  // stride 20 dw: 2-way bank (free)
#pragma unroll
    for (int i = 0; i < 2; ++i) {
      float K[4], R[4], o[4];
#pragma unroll
      for (int r = 0; r < 4; ++r) {
        float sv = acc[i][j][r] + icr[i][r] * (t0r[i][r] * e0 + t1r[i][r] * e1) + bi;
        // KAF geometric recurrence: G=-0.705078125, 2G*dp=-0.59375, G*dp^2=-0.125 (exact)
        float tt = fminf(fmaxf(sv, -40.f), 40.f);
        float dd = tt + 4.0f;
        K[r] = __expf(-0.705078125f * dd * dd);
        R[r] = __expf(0.59375f * dd - 0.125f);
        o[r] = 0.f;
      }
#pragma unroll
      for (int d = 0; d < 20; ++d) {
        o[0] += a20[d] * K[0]; K[0] *= R[0]; R[0] *= WM;
        o[1] += a20[d] * K[1]; K[1] *= R[1]; R[1] *= WM;
        o[2] += a20[d] * K[2]; K[2] *= R[2]; R[2] *= WM;
        o[3] += a20[d] * K[3]; K[3] *= R[3]; R[3] *= WM;
      }
      const int rw0 = rowb + 16 * i;
      if (final_layer) {
#pragma unroll
        for (int r = 0; r < 4; ++r)
          if (rw0 + r < N_NODES) fout[(size_t)(rw0 + r) * 256 + cn] = o[r];
      } else {
#pragma unroll
        for (int r = 0; r < 4; ++r)
          if (rw0 + r < N_NODES) hout[(size_t)(rw0 + r) * 256 + cn] = (_Float16)o[r];
      }
    }
  }
}

// ---------------- launch ----------------
extern "C" void kernel_launch(void* const* d_in, const int* in_sizes, int n_in,
                              void* d_out, int out_size, void* d_ws, size_t ws_size,
                              hipStream_t stream) {
  const float* x       = (const float*)d_in[0];
  const int*   ei      = (const int*)d_in[1];
  const float* ea      = (const float*)d_in[2];
  const float* node_w  = (const float*)d_in[3];
  const float* edge_w  = (const float*)d_in[4];
  const float* neigh_w = (const float*)d_in[5];
  const float* bias    = (const float*)d_in[6];
  const float* alpha   = (const float*)d_in[7];

  char* w = (char*)d_ws;
  int*            rs     = (int*)(w + OFF_RS);
  float*          invc   = (float*)(w + OFF_INVC);
  float*          s2     = (float*)(w + OFF_S2);
  unsigned short* colv   = (unsigned short*)(w + OFF_COLV);
  _Float16*       wcatT  = (_Float16*)(w + OFF_WCAT);
  _Float16*       hA     = (_Float16*)(w + OFF_HA);
  _Float16*       hB     = (_Float16*)(w + OFF_HB);
  _Float16*       g      = (_Float16*)(w + OFF_G);
  unsigned short* percnt = (unsigned short*)(w + OFF_PERC);
  int*            prefix = (int*)(w + OFF_BASE);
  int*            cnttot = (int*)(w + OFF_CTOT);
  int*            tick   = (int*)(w + OFF_TICK);
  float*          fout   = (float*)d_out;
  float2*         s2part = (float2*)d_out;   // 6.4 MB scratch; d_out dead until final gemm2

  k_prepc<<<B_PRE + 384 + 625, 1024, 0, stream>>>((const float4*)x, (half4*)hA,
                                                  neigh_w, node_w, wcatT, ei, ea, percnt,
                                                  s2part, tick);
  k_base<<<80, 256, 0, stream>>>(percnt, s2part, prefix, cnttot, rs, invc, s2, tick);
  k_scat<<<B_PRE, 1024, 0, stream>>>(ei, prefix, rs, colv);

  _Float16* hin = hA;
  for (int l = 0; l < 3; ++l) {
    k_aggr<<<2500, 256, 0, stream>>>(rs, colv, invc, hin, g);
    _Float16* hout = (l == 0) ? hB : hA;
    k_gemm2<<<dim3(157, 4), 256, 0, stream>>>(g, hin, wcatT + (size_t)l * 131072,
                                              edge_w + l * 512, bias + l * 256, alpha + l * 5120,
                                              invc, s2, hout, fout, (l == 2) ? 1 : 0);
    hin = hout;
  }
}

// Round 11
// 209.649 us; speedup vs baseline: 1.0515x; 1.0450x over previous
//
#include <hip/hip_runtime.h>
#include <hip/hip_bf16.h>

#define N_NODES 10000
#define N_EDGES 320000
#define B_PRE   80
#define EPB     (N_EDGES / B_PRE)   // 4000
#define SLK     130                 // GEMM LDS row stride (halves): 65 dw, odd -> 16-bank spread

typedef __attribute__((ext_vector_type(8))) _Float16 half8;
typedef __attribute__((ext_vector_type(4))) _Float16 half4;
typedef __attribute__((ext_vector_type(4))) float floatx4;

// ---- ws offsets (bytes), total ~16.95 MB ----
#define OFF_RS    0           // rs: 10001 int
#define OFF_INVC  40960       // invc: 10000 f32
#define OFF_S2    81920       // s2: 20000 f32
#define OFF_COLV  163840      // colv: 320000 u16
#define OFF_WCAT  806912      // wcat2T: 3*256*512 f16 = 786432 B
#define OFF_HA    1593344     // hA: 10000*256 f16
#define OFF_HB    6713344     // hB: 10000*256 f16
#define OFF_G     11833344    // g:  10000*256 f16
// preproc scratch aliased into g (dead until first k_aggr):
#define OFF_PERC  OFF_G                   // 80*10000 u16 = 1.6 MB
#define OFF_BASE  (OFF_G + 1600000)       // 80*10000 int = 3.2 MB
#define OFF_CTOT  (OFF_G + 4800000)       // 10000 int = 40 KB
// s2 partials (80*10000 float2 = 6.4 MB) live in d_out (dead until final gemm2)

// ---------------- fused: per-block degree count + s2 partials (0..79)
//                  + weight pack (80..463) + x->f16 convert (464..1088) ----------------
__global__ __launch_bounds__(1024) void k_prepc(const float4* __restrict__ x, half4* __restrict__ hA,
                                                const float* __restrict__ neigh_w, const float* __restrict__ node_w,
                                                _Float16* __restrict__ wcatT,
                                                const int* __restrict__ ei, const float* __restrict__ ea,
                                                unsigned short* __restrict__ percnt,
                                                float2* __restrict__ s2part) {
  __shared__ int hist[N_NODES];                   // 40KB; aliased as transpose tile by pack blocks
  __shared__ float2 sxy[N_NODES];                 // 80KB edge-attr partial sums
  const int tid = threadIdx.x, b = blockIdx.x;

  if (b < B_PRE) {
    // ---- degree count + edge-attr partial sums (LDS atomics, CU-local) ----
    for (int n = tid; n < N_NODES; n += 1024) { hist[n] = 0; sxy[n] = make_float2(0.f, 0.f); }
    __syncthreads();
    const int e0 = b * EPB;
    for (int e = e0 + tid; e < e0 + EPB; e += 1024) {
      int d = ei[N_EDGES + e];
      float2 a = ((const float2*)ea)[e];
      atomicAdd(&hist[d], 1);
      atomicAdd(&sxy[d].x, a.x);                  // ds_add_f32
      atomicAdd(&sxy[d].y, a.y);
    }
    __syncthreads();
    for (int n = tid; n < N_NODES; n += 1024) {
      percnt[b * N_NODES + n] = (unsigned short)hist[n];
      s2part[b * N_NODES + n] = sxy[n];           // coalesced float2 store
    }
    return;
  }
  if (b < B_PRE + 384) {
    // ---- pack B^T: wcat2T[l][n(256)][k(512)] = (k<256 ? neigh_w[l][k][n] : node_w[l][k-256][n])
    float (*t)[33] = (float(*)[33])hist;          // 32x33 tile aliased over hist
    const int bb = b - B_PRE;                     // 384 = 16 k-tiles x 8 n-tiles x 3 layers
    const int k0 = (bb & 15) * 32;
    const int n0 = ((bb >> 4) & 7) * 32;
    const int l  = bb >> 7;
    const int r = tid >> 5, c = tid & 31;         // 32x32 = 1024 threads, 1 elem each
    const float* src = (k0 < 256) ? neigh_w : node_w;
    const int kb = (k0 < 256) ? k0 : (k0 - 256);
    t[r][c] = src[l * 65536 + (kb + r) * 256 + (n0 + c)];       // coalesced in n
    __syncthreads();
    wcatT[(size_t)l * 131072 + (n0 + r) * 512 + (k0 + c)] = (_Float16)t[c][r];  // coalesced in k
    return;
  }
  // ---- x -> f16 convert: 625 blocks x 1024 = 640000 float4 exactly ----
  int i = (b - (B_PRE + 384)) * 1024 + tid;
  float4 v = x[i];
  half4 h; h.x = (_Float16)v.x; h.y = (_Float16)v.y; h.z = (_Float16)v.z; h.w = (_Float16)v.w;
  hA[i] = h;
}

// per-node cross-block prefix + degree total + s2 final reduce (all coalesced streams)
__global__ __launch_bounds__(256) void k_base(const unsigned short* __restrict__ percnt,
                                              const float2* __restrict__ s2part,
                                              int* __restrict__ prefix, int* __restrict__ cnttot,
                                              float* __restrict__ s2) {
  int n = blockIdx.x * 256 + threadIdx.x;
  if (n >= N_NODES) return;
  int s = 0;
  float sx = 0.f, sy = 0.f;
  for (int b = 0; b < B_PRE; ++b) {
    prefix[b * N_NODES + n] = s;
    s += (int)percnt[b * N_NODES + n];
    float2 p = s2part[b * N_NODES + n];
    sx += p.x; sy += p.y;
  }
  cnttot[n] = s;
  s2[2 * n] = sx; s2[2 * n + 1] = sy;
}

__global__ __launch_bounds__(1024) void k_scan(const int* __restrict__ cnttot,
                                               int* __restrict__ rs, float* __restrict__ invc) {
  __shared__ int lds[1024];
  const int t = threadIdx.x;
  const int base = t * 10;
  int loc[10];
  int sum = 0;
#pragma unroll
  for (int i = 0; i < 10; ++i) {
    int idx = base + i;
    int v = (idx < N_NODES) ? cnttot[idx] : 0;
    loc[i] = v; sum += v;
  }
  lds[t] = sum; __syncthreads();
  for (int off = 1; off < 1024; off <<= 1) {
    int v = 0;
    if (t >= off) v = lds[t - off];
    __syncthreads();
    if (t >= off) lds[t] += v;
    __syncthreads();
  }
  int ex = lds[t] - sum;
#pragma unroll
  for (int i = 0; i < 10; ++i) {
    int idx = base + i;
    if (idx < N_NODES) {
      rs[idx] = ex; ex += loc[i];
      invc[idx] = (loc[i] > 0) ? (1.0f / (float)loc[i]) : 0.0f;
    }
  }
  if (t == 1023) rs[N_NODES] = lds[1023];
}

// scatter colv into CSR order (plain stores; no edge-attr work)
__global__ __launch_bounds__(1024) void k_scat(const int* __restrict__ ei,
                                               const int* __restrict__ prefix, const int* __restrict__ rs,
                                               unsigned short* __restrict__ colv) {
  __shared__ int cur[N_NODES];
  const int t = threadIdx.x, b = blockIdx.x;
  for (int n = t; n < N_NODES; n += 1024)
    cur[n] = rs[n] + prefix[b * N_NODES + n];
  __syncthreads();
  const int e0 = b * EPB;
  for (int e = e0 + t; e < e0 + EPB; e += 1024) {
    int d = ei[N_EDGES + e];
    int src = ei[e];
    int pos = atomicAdd(&cur[d], 1);             // LDS atomic
    colv[pos] = (unsigned short)src;
  }
}

// ---------------- aggregate h first (linearity): g[n] = invc[n] * sum_{src in N(n)} h[src] ----------------
// One node per wave (10000 waves), 16 edges / 8 row-loads in flight per half-wave.
__global__ __launch_bounds__(256) void k_aggr(const int* __restrict__ rs, const unsigned short* __restrict__ colv,
                                              const float* __restrict__ invc,
                                              const _Float16* __restrict__ H, _Float16* __restrict__ Gm) {
  const int wv   = threadIdx.x >> 6;
  const int lane = threadIdx.x & 63;
  const int hf   = lane >> 5;
  const int l5   = lane & 31;
  const int n = blockIdx.x * 4 + wv;   // 2500*4 == N_NODES
  int beg = rs[n], end = rs[n + 1];
  beg = max(0, min(beg, N_EDGES));
  end = max(beg, min(end, N_EDGES));
  const int co = l5 * 8;               // this half-lane's channel offset (x8 f16)

  half8 a0 = (half8)(_Float16)0.f, a1 = (half8)(_Float16)0.f;
  half8 a2 = (half8)(_Float16)0.f, a3 = (half8)(_Float16)0.f;
  half8 a4 = (half8)(_Float16)0.f, a5 = (half8)(_Float16)0.f;
  half8 a6 = (half8)(_Float16)0.f, a7 = (half8)(_Float16)0.f;
  for (int base = beg; base < end; base += 64) {
    const int cnt = min(64, end - base);
    int myIdx = 0;
    if (base + lane < end) myIdx = (int)colv[base + lane];   // coalesced index load
    int j = 0;
    for (; j + 16 <= cnt; j += 16) {                         // 16 edges / 8 loads in flight
      int s[8];
#pragma unroll
      for (int k = 0; k < 8; ++k) s[k] = __shfl(myIdx, j + 2 * k + hf);
      half8 v[8];
#pragma unroll
      for (int k = 0; k < 8; ++k) v[k] = *(const half8*)(H + (size_t)s[k] * 256 + co);
      a0 += v[0]; a1 += v[1]; a2 += v[2]; a3 += v[3];
      a4 += v[4]; a5 += v[5]; a6 += v[6]; a7 += v[7];
    }
    for (; j + 8 <= cnt; j += 8) {                           // 8 edges / 4 loads
      int s0 = __shfl(myIdx, j + hf);
      int s1 = __shfl(myIdx, j + 2 + hf);
      int s2i = __shfl(myIdx, j + 4 + hf);
      int s3 = __shfl(myIdx, j + 6 + hf);
      half8 v0 = *(const half8*)(H + (size_t)s0 * 256 + co);
      half8 v1 = *(const half8*)(H + (size_t)s1 * 256 + co);
      half8 v2 = *(const half8*)(H + (size_t)s2i * 256 + co);
      half8 v3 = *(const half8*)(H + (size_t)s3 * 256 + co);
      a0 += v0; a1 += v1; a2 += v2; a3 += v3;
    }
    for (; j + 2 <= cnt; j += 2) {
      int s0 = __shfl(myIdx, j + hf);
      a0 += *(const half8*)(H + (size_t)s0 * 256 + co);
    }
    if (j < cnt) {
      int s0 = __shfl(myIdx, j);
      if (hf == 0)
        a0 += *(const half8*)(H + (size_t)s0 * 256 + co);
    }
  }
  half8 acc0 = ((a0 + a4) + (a1 + a5)) + ((a2 + a6) + (a3 + a7));
  // combine the two half-waves (same channels, different edges)
  union { half8 h; unsigned int u[4]; } me, ot;
  me.h = acc0;
#pragma unroll
  for (int r = 0; r < 4; ++r) ot.u[r] = (unsigned int)__shfl_xor((int)me.u[r], 32);
  acc0 = me.h + ot.h;

  if (hf == 0) {
    const float ic = invc[n];
    half8 o;
#pragma unroll
    for (int k = 0; k < 8; ++k) o[k] = (_Float16)((float)acc0[k] * ic);
    *(half8*)(Gm + (size_t)n * 256 + co) = o;   // 32 lanes x 16B = full 512B row
  }
}

// ---------------- GEMM [g | h] (Nx512) @ B^T(256x512) + fused update + KAF epilogue ----------------
// 64x64 tile, BK=128, K=512 -> 4 kt iters. LDS 38.4KB -> 4 blocks/CU.
__global__ __launch_bounds__(256) void k_gemm2(const _Float16* __restrict__ Gm,  // [N][256] f16
                                               const _Float16* __restrict__ Hm,  // [N][256] f16
                                               const _Float16* __restrict__ BT,  // [256][512] f16
                                               const float* __restrict__ ew,     // [2][256] f32
                                               const float* __restrict__ bias,   // [256]    f32
                                               const float* __restrict__ alpha,  // [256][20] f32
                                               const float* __restrict__ invc,
                                               const float* __restrict__ s2,
                                               _Float16* __restrict__ hout, float* __restrict__ fout,
                                               int final_layer) {
  __shared__ _Float16 As[64 * SLK];
  __shared__ _Float16 Bs[64 * SLK];
  __shared__ float alds[64 * 20];      // alpha rows for this block's 64 output cols
  const int tid = threadIdx.x;
  const int wv = tid >> 6;
  const int lane = tid & 63;
  const int m0 = blockIdx.x * 64;
  const int n0 = blockIdx.y * 64;
  const int wy = wv >> 1, wx = wv & 1;

#pragma unroll
  for (int ii = 0; ii < 5; ++ii)       // 64 rows x 20 = 1280 floats, contiguous in alpha
    alds[tid + 256 * ii] = alpha[n0 * 20 + tid + 256 * ii];

  floatx4 acc[2][2];
#pragma unroll
  for (int i = 0; i < 2; ++i)
#pragma unroll
    for (int j = 0; j < 2; ++j) acc[i][j] = (floatx4){0.f, 0.f, 0.f, 0.f};

  const int mrow = 32 * wy + (lane & 15);
  const int nrow = 32 * wx + (lane & 15);
  const int q8 = (lane >> 4) * 8;

#pragma unroll
  for (int kt = 0; kt < 4; ++kt) {     // K=512 / BK=128
    const _Float16* Asrc = (kt < 2) ? Gm : Hm;   // first 256 k's: g, last 256: h
    const int ko = (kt & 1) * 128;
    half8 av[4], bv[4];
#pragma unroll
    for (int c = 0; c < 4; ++c) {
      int ch = tid + 256 * c;            // 0..1023
      int row = ch >> 4;
      int off = (ch & 15) * 8;
      int arow = m0 + row; if (arow >= N_NODES) arow = N_NODES - 1;
      av[c] = *(const half8*)(Asrc + (size_t)arow * 256 + ko + off);
      bv[c] = *(const half8*)(BT + (size_t)(n0 + row) * 512 + kt * 128 + off);
    }
    __syncthreads();                     // prev iter's LDS reads complete
#pragma unroll
    for (int c = 0; c < 4; ++c) {
      int ch = tid + 256 * c;
      int row = ch >> 4;
      int off = (ch & 15) * 8;
      *(half8*)&As[row * SLK + off] = av[c];
      *(half8*)&Bs[row * SLK + off] = bv[c];
    }
    __syncthreads();
#pragma unroll
    for (int ks = 0; ks < 4; ++ks) {
      const int kb = ks * 32 + q8;
      half8 af0 = *(const half8*)&As[mrow * SLK + kb];
      half8 af1 = *(const half8*)&As[(mrow + 16) * SLK + kb];
      half8 bf0 = *(const half8*)&Bs[nrow * SLK + kb];
      half8 bf1 = *(const half8*)&Bs[(nrow + 16) * SLK + kb];
      acc[0][0] = __builtin_amdgcn_mfma_f32_16x16x32_f16(af0, bf0, acc[0][0], 0, 0, 0);
      acc[0][1] = __builtin_amdgcn_mfma_f32_16x16x32_f16(af0, bf1, acc[0][1], 0, 0, 0);
      acc[1][0] = __builtin_amdgcn_mfma_f32_16x16x32_f16(af1, bf0, acc[1][0], 0, 0, 0);
      acc[1][1] = __builtin_amdgcn_mfma_f32_16x16x32_f16(af1, bf1, acc[1][1], 0, 0, 0);
    }
  }

  // ---- fused update + KAF epilogue ----
  // C/D layout: col = lane&15, row = 4*(lane>>4) + r
  const int rowb = m0 + 32 * wy + 4 * (lane >> 4);
  const int clb  = 32 * wx + (lane & 15);    // local col in [0,64)
  float icr[2][4], t0r[2][4], t1r[2][4];
#pragma unroll
  for (int i = 0; i < 2; ++i)
#pragma unroll
    for (int r = 0; r < 4; ++r) {
      int rw = rowb + 16 * i + r;
      int rc = (rw < N_NODES) ? rw : (N_NODES - 1);
      icr[i][r] = invc[rc];
      t0r[i][r] = s2[2 * rc];
      t1r[i][r] = s2[2 * rc + 1];
    }
  const float WM = 0.7788007831f;      // exp(-0.25)
#pragma unroll
  for (int j = 0; j < 2; ++j) {
    const int cl = clb + 16 * j;
    const int cn = n0 + cl;
    const float e0 = ew[cn], e1 = ew[256 + cn], bi = bias[cn];
    float a20[20];
#pragma unroll
    for (int q = 0; q < 5; ++q)
      *(float4*)&a20[4 * q] = *(const float4*)&alds[cl * 20 + 4 * q];  // stride 20 dw: 2-way bank (free)
#pragma unroll
    for (int i = 0; i < 2; ++i) {
      float K[4], R[4], o[4];
#pragma unroll
      for (int r = 0; r < 4; ++r) {
        float sv = acc[i][j][r] + icr[i][r] * (t0r[i][r] * e0 + t1r[i][r] * e1) + bi;
        // KAF geometric recurrence: G=-0.705078125, 2G*dp=-0.59375, G*dp^2=-0.125 (exact)
        float tt = fminf(fmaxf(sv, -40.f), 40.f);
        float dd = tt + 4.0f;
        K[r] = __expf(-0.705078125f * dd * dd);
        R[r] = __expf(0.59375f * dd - 0.125f);
        o[r] = 0.f;
      }
#pragma unroll
      for (int d = 0; d < 20; ++d) {
        o[0] += a20[d] * K[0]; K[0] *= R[0]; R[0] *= WM;
        o[1] += a20[d] * K[1]; K[1] *= R[1]; R[1] *= WM;
        o[2] += a20[d] * K[2]; K[2] *= R[2]; R[2] *= WM;
        o[3] += a20[d] * K[3]; K[3] *= R[3]; R[3] *= WM;
      }
      const int rw0 = rowb + 16 * i;
      if (final_layer) {
#pragma unroll
        for (int r = 0; r < 4; ++r)
          if (rw0 + r < N_NODES) fout[(size_t)(rw0 + r) * 256 + cn] = o[r];
      } else {
#pragma unroll
        for (int r = 0; r < 4; ++r)
          if (rw0 + r < N_NODES) hout[(size_t)(rw0 + r) * 256 + cn] = (_Float16)o[r];
      }
    }
  }
}

// ---------------- launch ----------------
extern "C" void kernel_launch(void* const* d_in, const int* in_sizes, int n_in,
                              void* d_out, int out_size, void* d_ws, size_t ws_size,
                              hipStream_t stream) {
  const float* x       = (const float*)d_in[0];
  const int*   ei      = (const int*)d_in[1];
  const float* ea      = (const float*)d_in[2];
  const float* node_w  = (const float*)d_in[3];
  const float* edge_w  = (const float*)d_in[4];
  const float* neigh_w = (const float*)d_in[5];
  const float* bias    = (const float*)d_in[6];
  const float* alpha   = (const float*)d_in[7];

  char* w = (char*)d_ws;
  int*            rs     = (int*)(w + OFF_RS);
  float*          invc   = (float*)(w + OFF_INVC);
  float*          s2     = (float*)(w + OFF_S2);
  unsigned short* colv   = (unsigned short*)(w + OFF_COLV);
  _Float16*       wcatT  = (_Float16*)(w + OFF_WCAT);
  _Float16*       hA     = (_Float16*)(w + OFF_HA);
  _Float16*       hB     = (_Float16*)(w + OFF_HB);
  _Float16*       g      = (_Float16*)(w + OFF_G);
  unsigned short* percnt = (unsigned short*)(w + OFF_PERC);
  int*            prefix = (int*)(w + OFF_BASE);
  int*            cnttot = (int*)(w + OFF_CTOT);
  float*          fout   = (float*)d_out;
  float2*         s2part = (float2*)d_out;   // 6.4 MB scratch; d_out dead until final gemm2

  k_prepc<<<B_PRE + 384 + 625, 1024, 0, stream>>>((const float4*)x, (half4*)hA,
                                                  neigh_w, node_w, wcatT, ei, ea, percnt, s2part);
  k_base<<<40, 256, 0, stream>>>(percnt, s2part, prefix, cnttot, s2);
  k_scan<<<1, 1024, 0, stream>>>(cnttot, rs, invc);
  k_scat<<<B_PRE, 1024, 0, stream>>>(ei, prefix, rs, colv);

  _Float16* hin = hA;
  for (int l = 0; l < 3; ++l) {
    k_aggr<<<2500, 256, 0, stream>>>(rs, colv, invc, hin, g);
    _Float16* hout = (l == 0) ? hB : hA;
    k_gemm2<<<dim3(157, 4), 256, 0, stream>>>(g, hin, wcatT + (size_t)l * 131072,
                                              edge_w + l * 512, bias + l * 256, alpha + l * 5120,
                                              invc, s2, hout, fout, (l == 2) ? 1 : 0);
    hin = hout;
  }
}

// Round 12
// 206.709 us; speedup vs baseline: 1.0664x; 1.0142x over previous
//
#include <hip/hip_runtime.h>
#include <hip/hip_bf16.h>

#define N_NODES 10000
#define N_EDGES 320000
#define B_PRE   80
#define EPB     (N_EDGES / B_PRE)   // 4000
#define SLK     130                 // GEMM LDS row stride (halves): 65 dw, odd -> 16-bank spread

typedef __attribute__((ext_vector_type(8))) _Float16 half8;
typedef __attribute__((ext_vector_type(4))) _Float16 half4;
typedef __attribute__((ext_vector_type(4))) float floatx4;

// ---- ws offsets (bytes), total ~16.95 MB ----
#define OFF_RS    0           // rs: 10001 int
#define OFF_INVC  40960       // invc: 10000 f32
#define OFF_S2    81920       // s2: 20000 f32
#define OFF_COLV  163840      // colv: 320000 u16
#define OFF_WCAT  806912      // wcat2T: 3*256*512 f16 = 786432 B
#define OFF_HA    1593344     // hA: 10000*256 f16
#define OFF_HB    6713344     // hB: 10000*256 f16
#define OFF_G     11833344    // g:  10000*256 f16
// preproc scratch aliased into g (dead until first k_aggr):
#define OFF_PERC  OFF_G                   // 80*10000 u16 = 1.6 MB
#define OFF_BASE  (OFF_G + 1600000)       // 80*10000 int = 3.2 MB
#define OFF_CTOT  (OFF_G + 4800000)       // 10000 int = 40 KB
// s2 partials (80*10000 float2 = 6.4 MB) live in d_out (dead until final gemm2)

// ---------------- fused: per-block degree count + s2 partials (0..79)
//                  + weight pack (80..463) + x->f16 convert (464..1088) ----------------
__global__ __launch_bounds__(1024) void k_prepc(const float4* __restrict__ x, half4* __restrict__ hA,
                                                const float* __restrict__ neigh_w, const float* __restrict__ node_w,
                                                _Float16* __restrict__ wcatT,
                                                const int* __restrict__ ei, const float* __restrict__ ea,
                                                unsigned short* __restrict__ percnt,
                                                float2* __restrict__ s2part) {
  __shared__ int hist[N_NODES];                   // 40KB; aliased as transpose tile by pack blocks
  __shared__ float2 sxy[N_NODES];                 // 80KB edge-attr partial sums
  const int tid = threadIdx.x, b = blockIdx.x;

  if (b < B_PRE) {
    // ---- degree count + edge-attr partial sums (LDS atomics, CU-local) ----
    for (int n = tid; n < N_NODES; n += 1024) { hist[n] = 0; sxy[n] = make_float2(0.f, 0.f); }
    __syncthreads();
    const int e0 = b * EPB;
    for (int e = e0 + tid; e < e0 + EPB; e += 1024) {
      int d = ei[N_EDGES + e];
      float2 a = ((const float2*)ea)[e];
      atomicAdd(&hist[d], 1);
      atomicAdd(&sxy[d].x, a.x);                  // ds_add_f32
      atomicAdd(&sxy[d].y, a.y);
    }
    __syncthreads();
    for (int n = tid; n < N_NODES; n += 1024) {
      percnt[b * N_NODES + n] = (unsigned short)hist[n];
      s2part[b * N_NODES + n] = sxy[n];           // coalesced float2 store
    }
    return;
  }
  if (b < B_PRE + 384) {
    // ---- pack B^T: wcat2T[l][n(256)][k(512)] = (k<256 ? neigh_w[l][k][n] : node_w[l][k-256][n])
    float (*t)[33] = (float(*)[33])hist;          // 32x33 tile aliased over hist
    const int bb = b - B_PRE;                     // 384 = 16 k-tiles x 8 n-tiles x 3 layers
    const int k0 = (bb & 15) * 32;
    const int n0 = ((bb >> 4) & 7) * 32;
    const int l  = bb >> 7;
    const int r = tid >> 5, c = tid & 31;         // 32x32 = 1024 threads, 1 elem each
    const float* src = (k0 < 256) ? neigh_w : node_w;
    const int kb = (k0 < 256) ? k0 : (k0 - 256);
    t[r][c] = src[l * 65536 + (kb + r) * 256 + (n0 + c)];       // coalesced in n
    __syncthreads();
    wcatT[(size_t)l * 131072 + (n0 + r) * 512 + (k0 + c)] = (_Float16)t[c][r];  // coalesced in k
    return;
  }
  // ---- x -> f16 convert: 625 blocks x 1024 = 640000 float4 exactly ----
  int i = (b - (B_PRE + 384)) * 1024 + tid;
  float4 v = x[i];
  half4 h; h.x = (_Float16)v.x; h.y = (_Float16)v.y; h.z = (_Float16)v.z; h.w = (_Float16)v.w;
  hA[i] = h;
}

// per-node cross-block prefix + degree total + s2 final reduce (all coalesced streams)
__global__ __launch_bounds__(256) void k_base(const unsigned short* __restrict__ percnt,
                                              const float2* __restrict__ s2part,
                                              int* __restrict__ prefix, int* __restrict__ cnttot,
                                              float* __restrict__ s2) {
  int n = blockIdx.x * 256 + threadIdx.x;
  if (n >= N_NODES) return;
  int s = 0;
  float sx = 0.f, sy = 0.f;
  for (int b = 0; b < B_PRE; ++b) {
    prefix[b * N_NODES + n] = s;
    s += (int)percnt[b * N_NODES + n];
    float2 p = s2part[b * N_NODES + n];
    sx += p.x; sy += p.y;
  }
  cnttot[n] = s;
  s2[2 * n] = sx; s2[2 * n + 1] = sy;
}

// scatter colv into CSR order. Each block redundantly computes the exclusive scan of
// cnttot in LDS (cheap, no cross-block sync) -> deletes the k_scan dispatch + gap.
// Block 0 also publishes rs/invc for k_aggr (stream-ordered before first use).
__global__ __launch_bounds__(1024) void k_scat(const int* __restrict__ ei,
                                               const int* __restrict__ prefix,
                                               const int* __restrict__ cnttot,
                                               int* __restrict__ rs, float* __restrict__ invc,
                                               unsigned short* __restrict__ colv) {
  __shared__ int cur[N_NODES];                    // 40KB cursor array
  __shared__ int slds[1024];                      // 4KB scan scratch
  const int t = threadIdx.x, b = blockIdx.x;

  // ---- redundant per-block exclusive scan over 10000 cnttot ----
  const int base = t * 10;
  int loc[10];
  int sum = 0;
#pragma unroll
  for (int i = 0; i < 10; ++i) {
    int idx = base + i;
    int v = (idx < N_NODES) ? cnttot[idx] : 0;
    loc[i] = v; sum += v;
  }
  slds[t] = sum; __syncthreads();
  for (int off = 1; off < 1024; off <<= 1) {
    int v = 0;
    if (t >= off) v = slds[t - off];
    __syncthreads();
    if (t >= off) slds[t] += v;
    __syncthreads();
  }
  int ex = slds[t] - sum;
#pragma unroll
  for (int i = 0; i < 10; ++i) {
    int idx = base + i;
    if (idx < N_NODES) {
      cur[idx] = ex + prefix[b * N_NODES + idx];
      if (b == 0) {
        rs[idx] = ex;
        invc[idx] = (loc[i] > 0) ? (1.0f / (float)loc[i]) : 0.0f;
      }
      ex += loc[i];
    }
  }
  if (b == 0 && t == 1023) rs[N_NODES] = slds[1023];
  __syncthreads();

  // ---- scatter ----
  const int e0 = b * EPB;
  for (int e = e0 + t; e < e0 + EPB; e += 1024) {
    int d = ei[N_EDGES + e];
    int src = ei[e];
    int pos = atomicAdd(&cur[d], 1);             // LDS atomic
    colv[pos] = (unsigned short)src;
  }
}

// ---------------- aggregate h first (linearity): g[n] = invc[n] * sum_{src in N(n)} h[src] ----------------
// One node per wave (10000 waves), 16 edges / 8 row-loads in flight per half-wave.
__global__ __launch_bounds__(256) void k_aggr(const int* __restrict__ rs, const unsigned short* __restrict__ colv,
                                              const float* __restrict__ invc,
                                              const _Float16* __restrict__ H, _Float16* __restrict__ Gm) {
  const int wv   = threadIdx.x >> 6;
  const int lane = threadIdx.x & 63;
  const int hf   = lane >> 5;
  const int l5   = lane & 31;
  const int n = blockIdx.x * 4 + wv;   // 2500*4 == N_NODES
  int beg = rs[n], end = rs[n + 1];
  beg = max(0, min(beg, N_EDGES));
  end = max(beg, min(end, N_EDGES));
  const int co = l5 * 8;               // this half-lane's channel offset (x8 f16)

  half8 a0 = (half8)(_Float16)0.f, a1 = (half8)(_Float16)0.f;
  half8 a2 = (half8)(_Float16)0.f, a3 = (half8)(_Float16)0.f;
  half8 a4 = (half8)(_Float16)0.f, a5 = (half8)(_Float16)0.f;
  half8 a6 = (half8)(_Float16)0.f, a7 = (half8)(_Float16)0.f;
  for (int base = beg; base < end; base += 64) {
    const int cnt = min(64, end - base);
    int myIdx = 0;
    if (base + lane < end) myIdx = (int)colv[base + lane];   // coalesced index load
    int j = 0;
    for (; j + 16 <= cnt; j += 16) {                         // 16 edges / 8 loads in flight
      int s[8];
#pragma unroll
      for (int k = 0; k < 8; ++k) s[k] = __shfl(myIdx, j + 2 * k + hf);
      half8 v[8];
#pragma unroll
      for (int k = 0; k < 8; ++k) v[k] = *(const half8*)(H + (size_t)s[k] * 256 + co);
      a0 += v[0]; a1 += v[1]; a2 += v[2]; a3 += v[3];
      a4 += v[4]; a5 += v[5]; a6 += v[6]; a7 += v[7];
    }
    for (; j + 8 <= cnt; j += 8) {                           // 8 edges / 4 loads
      int s0 = __shfl(myIdx, j + hf);
      int s1 = __shfl(myIdx, j + 2 + hf);
      int s2i = __shfl(myIdx, j + 4 + hf);
      int s3 = __shfl(myIdx, j + 6 + hf);
      half8 v0 = *(const half8*)(H + (size_t)s0 * 256 + co);
      half8 v1 = *(const half8*)(H + (size_t)s1 * 256 + co);
      half8 v2 = *(const half8*)(H + (size_t)s2i * 256 + co);
      half8 v3 = *(const half8*)(H + (size_t)s3 * 256 + co);
      a0 += v0; a1 += v1; a2 += v2; a3 += v3;
    }
    for (; j + 2 <= cnt; j += 2) {
      int s0 = __shfl(myIdx, j + hf);
      a0 += *(const half8*)(H + (size_t)s0 * 256 + co);
    }
    if (j < cnt) {
      int s0 = __shfl(myIdx, j);
      if (hf == 0)
        a0 += *(const half8*)(H + (size_t)s0 * 256 + co);
    }
  }
  half8 acc0 = ((a0 + a4) + (a1 + a5)) + ((a2 + a6) + (a3 + a7));
  // combine the two half-waves (same channels, different edges)
  union { half8 h; unsigned int u[4]; } me, ot;
  me.h = acc0;
#pragma unroll
  for (int r = 0; r < 4; ++r) ot.u[r] = (unsigned int)__shfl_xor((int)me.u[r], 32);
  acc0 = me.h + ot.h;

  if (hf == 0) {
    const float ic = invc[n];
    half8 o;
#pragma unroll
    for (int k = 0; k < 8; ++k) o[k] = (_Float16)((float)acc0[k] * ic);
    *(half8*)(Gm + (size_t)n * 256 + co) = o;   // 32 lanes x 16B = full 512B row
  }
}

// ---------------- GEMM [g | h] (Nx512) @ B^T(256x512) + fused update + KAF epilogue ----------------
// 64x64 tile, BK=128, K=512 -> 4 kt iters. LDS 38.4KB -> 4 blocks/CU.
__global__ __launch_bounds__(256) void k_gemm2(const _Float16* __restrict__ Gm,  // [N][256] f16
                                               const _Float16* __restrict__ Hm,  // [N][256] f16
                                               const _Float16* __restrict__ BT,  // [256][512] f16
                                               const float* __restrict__ ew,     // [2][256] f32
                                               const float* __restrict__ bias,   // [256]    f32
                                               const float* __restrict__ alpha,  // [256][20] f32
                                               const float* __restrict__ invc,
                                               const float* __restrict__ s2,
                                               _Float16* __restrict__ hout, float* __restrict__ fout,
                                               int final_layer) {
  __shared__ _Float16 As[64 * SLK];
  __shared__ _Float16 Bs[64 * SLK];
  __shared__ float alds[64 * 20];      // alpha rows for this block's 64 output cols
  const int tid = threadIdx.x;
  const int wv = tid >> 6;
  const int lane = tid & 63;
  const int m0 = blockIdx.x * 64;
  const int n0 = blockIdx.y * 64;
  const int wy = wv >> 1, wx = wv & 1;

#pragma unroll
  for (int ii = 0; ii < 5; ++ii)       // 64 rows x 20 = 1280 floats, contiguous in alpha
    alds[tid + 256 * ii] = alpha[n0 * 20 + tid + 256 * ii];

  floatx4 acc[2][2];
#pragma unroll
  for (int i = 0; i < 2; ++i)
#pragma unroll
    for (int j = 0; j < 2; ++j) acc[i][j] = (floatx4){0.f, 0.f, 0.f, 0.f};

  const int mrow = 32 * wy + (lane & 15);
  const int nrow = 32 * wx + (lane & 15);
  const int q8 = (lane >> 4) * 8;

#pragma unroll
  for (int kt = 0; kt < 4; ++kt) {     // K=512 / BK=128
    const _Float16* Asrc = (kt < 2) ? Gm : Hm;   // first 256 k's: g, last 256: h
    const int ko = (kt & 1) * 128;
    half8 av[4], bv[4];
#pragma unroll
    for (int c = 0; c < 4; ++c) {
      int ch = tid + 256 * c;            // 0..1023
      int row = ch >> 4;
      int off = (ch & 15) * 8;
      int arow = m0 + row; if (arow >= N_NODES) arow = N_NODES - 1;
      av[c] = *(const half8*)(Asrc + (size_t)arow * 256 + ko + off);
      bv[c] = *(const half8*)(BT + (size_t)(n0 + row) * 512 + kt * 128 + off);
    }
    __syncthreads();                     // prev iter's LDS reads complete
#pragma unroll
    for (int c = 0; c < 4; ++c) {
      int ch = tid + 256 * c;
      int row = ch >> 4;
      int off = (ch & 15) * 8;
      *(half8*)&As[row * SLK + off] = av[c];
      *(half8*)&Bs[row * SLK + off] = bv[c];
    }
    __syncthreads();
#pragma unroll
    for (int ks = 0; ks < 4; ++ks) {
      const int kb = ks * 32 + q8;
      half8 af0 = *(const half8*)&As[mrow * SLK + kb];
      half8 af1 = *(const half8*)&As[(mrow + 16) * SLK + kb];
      half8 bf0 = *(const half8*)&Bs[nrow * SLK + kb];
      half8 bf1 = *(const half8*)&Bs[(nrow + 16) * SLK + kb];
      acc[0][0] = __builtin_amdgcn_mfma_f32_16x16x32_f16(af0, bf0, acc[0][0], 0, 0, 0);
      acc[0][1] = __builtin_amdgcn_mfma_f32_16x16x32_f16(af0, bf1, acc[0][1], 0, 0, 0);
      acc[1][0] = __builtin_amdgcn_mfma_f32_16x16x32_f16(af1, bf0, acc[1][0], 0, 0, 0);
      acc[1][1] = __builtin_amdgcn_mfma_f32_16x16x32_f16(af1, bf1, acc[1][1], 0, 0, 0);
    }
  }

  // ---- fused update + KAF epilogue ----
  // C/D layout: col = lane&15, row = 4*(lane>>4) + r
  const int rowb = m0 + 32 * wy + 4 * (lane >> 4);
  const int clb  = 32 * wx + (lane & 15);    // local col in [0,64)
  float icr[2][4], t0r[2][4], t1r[2][4];
#pragma unroll
  for (int i = 0; i < 2; ++i)
#pragma unroll
    for (int r = 0; r < 4; ++r) {
      int rw = rowb + 16 * i + r;
      int rc = (rw < N_NODES) ? rw : (N_NODES - 1);
      icr[i][r] = invc[rc];
      t0r[i][r] = s2[2 * rc];
      t1r[i][r] = s2[2 * rc + 1];
    }
  const float WM = 0.7788007831f;      // exp(-0.25)
#pragma unroll
  for (int j = 0; j < 2; ++j) {
    const int cl = clb + 16 * j;
    const int cn = n0 + cl;
    const float e0 = ew[cn], e1 = ew[256 + cn], bi = bias[cn];
    float a20[20];
#pragma unroll
    for (int q = 0; q < 5; ++q)
      *(float4*)&a20[4 * q] = *(const float4*)&alds[cl * 20 + 4 * q];  // stride 20 dw: 2-way bank (free)
#pragma unroll
    for (int i = 0; i < 2; ++i) {
      float K[4], R[4], o[4];
#pragma unroll
      for (int r = 0; r < 4; ++r) {
        float sv = acc[i][j][r] + icr[i][r] * (t0r[i][r] * e0 + t1r[i][r] * e1) + bi;
        // KAF geometric recurrence: G=-0.705078125, 2G*dp=-0.59375, G*dp^2=-0.125 (exact)
        float tt = fminf(fmaxf(sv, -40.f), 40.f);
        float dd = tt + 4.0f;
        K[r] = __expf(-0.705078125f * dd * dd);
        R[r] = __expf(0.59375f * dd - 0.125f);
        o[r] = 0.f;
      }
#pragma unroll
      for (int d = 0; d < 20; ++d) {
        o[0] += a20[d] * K[0]; K[0] *= R[0]; R[0] *= WM;
        o[1] += a20[d] * K[1]; K[1] *= R[1]; R[1] *= WM;
        o[2] += a20[d] * K[2]; K[2] *= R[2]; R[2] *= WM;
        o[3] += a20[d] * K[3]; K[3] *= R[3]; R[3] *= WM;
      }
      const int rw0 = rowb + 16 * i;
      if (final_layer) {
#pragma unroll
        for (int r = 0; r < 4; ++r)
          if (rw0 + r < N_NODES) fout[(size_t)(rw0 + r) * 256 + cn] = o[r];
      } else {
#pragma unroll
        for (int r = 0; r < 4; ++r)
          if (rw0 + r < N_NODES) hout[(size_t)(rw0 + r) * 256 + cn] = (_Float16)o[r];
      }
    }
  }
}

// ---------------- launch ----------------
extern "C" void kernel_launch(void* const* d_in, const int* in_sizes, int n_in,
                              void* d_out, int out_size, void* d_ws, size_t ws_size,
                              hipStream_t stream) {
  const float* x       = (const float*)d_in[0];
  const int*   ei      = (const int*)d_in[1];
  const float* ea      = (const float*)d_in[2];
  const float* node_w  = (const float*)d_in[3];
  const float* edge_w  = (const float*)d_in[4];
  const float* neigh_w = (const float*)d_in[5];
  const float* bias    = (const float*)d_in[6];
  const float* alpha   = (const float*)d_in[7];

  char* w = (char*)d_ws;
  int*            rs     = (int*)(w + OFF_RS);
  float*          invc   = (float*)(w + OFF_INVC);
  float*          s2     = (float*)(w + OFF_S2);
  unsigned short* colv   = (unsigned short*)(w + OFF_COLV);
  _Float16*       wcatT  = (_Float16*)(w + OFF_WCAT);
  _Float16*       hA     = (_Float16*)(w + OFF_HA);
  _Float16*       hB     = (_Float16*)(w + OFF_HB);
  _Float16*       g      = (_Float16*)(w + OFF_G);
  unsigned short* percnt = (unsigned short*)(w + OFF_PERC);
  int*            prefix = (int*)(w + OFF_BASE);
  int*            cnttot = (int*)(w + OFF_CTOT);
  float*          fout   = (float*)d_out;
  float2*         s2part = (float2*)d_out;   // 6.4 MB scratch; d_out dead until final gemm2

  k_prepc<<<B_PRE + 384 + 625, 1024, 0, stream>>>((const float4*)x, (half4*)hA,
                                                  neigh_w, node_w, wcatT, ei, ea, percnt, s2part);
  k_base<<<40, 256, 0, stream>>>(percnt, s2part, prefix, cnttot, s2);
  k_scat<<<B_PRE, 1024, 0, stream>>>(ei, prefix, cnttot, rs, invc, colv);

  _Float16* hin = hA;
  for (int l = 0; l < 3; ++l) {
    k_aggr<<<2500, 256, 0, stream>>>(rs, colv, invc, hin, g);
    _Float16* hout = (l == 0) ? hB : hA;
    k_gemm2<<<dim3(157, 4), 256, 0, stream>>>(g, hin, wcatT + (size_t)l * 131072,
                                              edge_w + l * 512, bias + l * 256, alpha + l * 5120,
                                              invc, s2, hout, fout, (l == 2) ? 1 : 0);
    hin = hout;
  }
}